// Round 10
// baseline (3946.156 us; speedup 1.0000x reference)
//
#include <hip/hip_runtime.h>

typedef __attribute__((ext_vector_type(8))) short bf16x8;
typedef __attribute__((ext_vector_type(4))) float f32x4;

#define MFMA_B16(A,B,C) __builtin_amdgcn_mfma_f32_16x16x32_bf16((A),(B),(C),0,0,0)

// ---- fragment layout constants (units: fragments of 1KB = 64 lanes * 8 bf16) ----
#define FO_ENC1 0
#define FO_PRI1 48
#define FO_DEC1 88
#define FO_GIH  136
#define FO_GHH  184
#define FO_ENC2 280
#define FO_PRI2 312
#define FO_DEC2 344
#define FO_MS   376
#define FO_DECMS 408
#define NFRAG   412

#define MS 200
#define TS 136

__device__ __forceinline__ unsigned short f2bf(float f) {
  union { float f; unsigned u; } v; v.f = f;
  unsigned r = (v.u + 0x7fffu + ((v.u >> 16) & 1u)) >> 16;
  return (unsigned short)r;
}
__device__ __forceinline__ float bf2f(unsigned short h) {
  union { unsigned u; float f; } v; v.u = ((unsigned)h) << 16;
  return v.f;
}
__device__ __forceinline__ float sigm_(float x) { return 1.f / (1.f + __expf(-x)); }
__device__ __forceinline__ float tanh_(float x) {
  x = fminf(fmaxf(x, -15.f), 15.f);
  float e = __expf(-2.f * x);
  return (1.f - e) / (1.f + e);
}
__device__ __forceinline__ float splus_(float x) {
  return fmaxf(x, 0.f) + log1pf(__expf(-fabsf(x)));
}

// ============================ PREP KERNEL ============================
// Master activation k-layout: [x:0..1 | z:2..33 | y:34..43 | pad:44..63 | h:64..191]
// Fragment (64 lanes x 8 bf16): lane l, elem j -> B[mk = kb*32 + (l>>4)*8 + j][n = nt*16 + (l&15)]
__global__ void prep_kernel(const float* __restrict__ ew1, const float* __restrict__ pw1,
                            const float* __restrict__ dw1, const float* __restrict__ wih,
                            const float* __restrict__ whh, const float* __restrict__ ew2,
                            const float* __restrict__ pw2, const float* __restrict__ dw2,
                            const float* __restrict__ emw, const float* __restrict__ esw,
                            const float* __restrict__ pmw, const float* __restrict__ psw,
                            const float* __restrict__ dmw, const float* __restrict__ dsw,
                            unsigned short* __restrict__ ws)
{
  int blk = blockIdx.x;
  int a = blk / NFRAG, f = blk % NFRAG;
  int l = threadIdx.x, lg = l >> 4, ln = l & 15;
  float v[8];

  if (f < FO_PRI1) {                       // enc1: [x, y, h]
    int fi = f, nt = fi / 6, kb = fi % 6, n = nt * 16 + ln;
#pragma unroll
    for (int j = 0; j < 8; ++j) {
      int mk = kb * 32 + lg * 8 + j;
      int r = (mk < 2) ? mk : (mk >= 34 && mk < 44) ? 2 + (mk - 34)
            : (mk >= 64) ? 12 + (mk - 64) : -1;
      v[j] = (r >= 0) ? ew1[((size_t)a * 140 + r) * 128 + n] : 0.f;
    }
  } else if (f < FO_DEC1) {                // pri1: [y, h]
    int fi = f - FO_PRI1, nt = fi / 5, kb = 1 + fi % 5, n = nt * 16 + ln;
#pragma unroll
    for (int j = 0; j < 8; ++j) {
      int mk = kb * 32 + lg * 8 + j;
      int r = (mk >= 34 && mk < 44) ? (mk - 34) : (mk >= 64) ? 10 + (mk - 64) : -1;
      v[j] = (r >= 0) ? pw1[((size_t)a * 138 + r) * 128 + n] : 0.f;
    }
  } else if (f < FO_GIH) {                 // dec1: [y, z, h]
    int fi = f - FO_DEC1, nt = fi / 6, kb = fi % 6, n = nt * 16 + ln;
#pragma unroll
    for (int j = 0; j < 8; ++j) {
      int mk = kb * 32 + lg * 8 + j;
      int r = (mk >= 2 && mk < 34) ? 10 + (mk - 2) : (mk >= 34 && mk < 44) ? (mk - 34)
            : (mk >= 64) ? 42 + (mk - 64) : -1;
      v[j] = (r >= 0) ? dw1[((size_t)a * 170 + r) * 128 + n] : 0.f;
    }
  } else if (f < FO_GHH) {                 // gru_ih: [x, z], N=384
    int fi = f - FO_GIH, nt = fi / 2, kb = fi % 2, n = nt * 16 + ln;
#pragma unroll
    for (int j = 0; j < 8; ++j) {
      int mk = kb * 32 + lg * 8 + j;
      v[j] = (mk < 34) ? wih[((size_t)a * 34 + mk) * 384 + n] : 0.f;
    }
  } else if (f < FO_ENC2) {                // gru_hh: K=128, N=384
    int fi = f - FO_GHH, nt = fi / 4, kb = fi % 4, n = nt * 16 + ln;
#pragma unroll
    for (int j = 0; j < 8; ++j) {
      int r = kb * 32 + lg * 8 + j;
      v[j] = whh[((size_t)a * 128 + r) * 384 + n];
    }
  } else if (f < FO_DEC2) {                // enc2 / pri2
    int fi = f - FO_ENC2;
    const float* W = (fi < 32) ? ew2 : pw2;
    fi &= 31;
    int nt = fi / 4, kb = fi % 4, n = nt * 16 + ln;
#pragma unroll
    for (int j = 0; j < 8; ++j) {
      int r = kb * 32 + lg * 8 + j;
      v[j] = W[((size_t)a * 128 + r) * 128 + n];
    }
  } else if (f < FO_MS) {                  // dec2
    int fi = f - FO_DEC2, nt = fi / 4, kb = fi % 4, n = nt * 16 + ln;
#pragma unroll
    for (int j = 0; j < 8; ++j) {
      int r = kb * 32 + lg * 8 + j;
      v[j] = dw2[((size_t)a * 128 + r) * 128 + n];
    }
  } else if (f < FO_DECMS) {               // enc_m / enc_s / pri_m / pri_s (N=32)
    int fi = f - FO_MS, mat = fi / 8, rem = fi % 8, nt = rem / 4, kb = rem % 4;
    int n = nt * 16 + ln;
    const float* W = (mat == 0) ? emw : (mat == 1) ? esw : (mat == 2) ? pmw : psw;
#pragma unroll
    for (int j = 0; j < 8; ++j) {
      int r = kb * 32 + lg * 8 + j;
      v[j] = W[((size_t)a * 128 + r) * 32 + n];
    }
  } else {                                 // dec m/s packed
    int kb = f - FO_DECMS;
#pragma unroll
    for (int j = 0; j < 8; ++j) {
      int r = kb * 32 + lg * 8 + j;
      v[j] = (ln < 2) ? dmw[((size_t)a * 128 + r) * 2 + ln]
           : (ln < 4) ? dsw[((size_t)a * 128 + r) * 2 + (ln - 2)] : 0.f;
    }
  }
  unsigned short* dst = ws + (size_t)blk * 512 + l * 8;
#pragma unroll
  for (int j = 0; j < 8; ++j) dst[j] = f2bf(v[j]);
}

// ============================ MAIN KERNEL ============================
// grid (16,5): 32 rows/block, 1024 threads = 16 waves (4/SIMD for latency hiding).
// Wave w: row-group rg=w>>3 (rows rg*16..+15), role wl=w&7 (same roles as the
// proven 8-wave structure). Per-wave register pressure is UNCHANGED vs the
// 16-row/8-wave version; only wave count doubles.
// ghh + dms pinned in LDS; other weights stream from L2 at point of use.
// Phases: A(enc1,pri1 | wl0: prev dec-head+NLL) | B(enc2,pri2) |
//   C(wl0-3: heads, wl0/1: z; wl4-7: ghh) | D(eps(t+1) wl0/1; dec1 wl0-3 + KL; gih+GRU wl4-7; xv wl0)
//   | E(dec2; h-write wl4-7; stage y(t+1) w1-5, x(t+2) w6)
#define LD_FRAG(idx) (*(const bf16x8*)(fa + (size_t)(idx) * 512 + l * 8))

__global__ __launch_bounds__(1024, 1) void vrnn_main(
    const float* __restrict__ states, const float* __restrict__ eps,
    const float* __restrict__ eb1, const float* __restrict__ eb2,
    const float* __restrict__ emb, const float* __restrict__ esb,
    const float* __restrict__ pb1, const float* __restrict__ pb2,
    const float* __restrict__ pmb, const float* __restrict__ psb,
    const float* __restrict__ db1, const float* __restrict__ db2,
    const float* __restrict__ dmb, const float* __restrict__ dsb,
    const float* __restrict__ bih, const float* __restrict__ bhh,
    const unsigned short* __restrict__ frags, float* __restrict__ out)
{
  const int a = blockIdx.y;
  const int b0 = blockIdx.x * 32;
  const int tid = threadIdx.x;
  const int w = tid >> 6, l = tid & 63, lg = l >> 4, ln = l & 15;
  const int wl = w & 7, rg = w >> 3, R = rg * 16;

  __shared__ __align__(16) unsigned short ghh_lds[96 * 512];   // 98304 B
  __shared__ __align__(16) unsigned short dms_lds[4 * 512];    //  4096 B
  __shared__ __align__(16) unsigned short master[32 * MS];     // 12800 B
  __shared__ __align__(16) unsigned short t1e[32 * TS], t1p[32 * TS];
  __shared__ __align__(16) unsigned short he[32 * TS], hp[32 * TS];  // 34816 B total
  __shared__ float msbuf[2][32][32];                           //  8192 B
  __shared__ float red[32];

  const unsigned short* fa = frags + (size_t)a * NFRAG * 512;

  // ---- pin LDS weight sets (once)
  {
    const uint4* s1 = (const uint4*)(fa + (size_t)FO_GHH * 512);
    uint4* d1 = (uint4*)ghh_lds;
    for (int i = tid; i < 96 * 64; i += 1024) d1[i] = s1[i];
    const uint4* s3 = (const uint4*)(fa + (size_t)FO_DECMS * 512);
    uint4* d3 = (uint4*)dms_lds;
    if (tid < 256) d3[tid] = s3[tid];
  }
  for (int i = tid; i < 32 * MS; i += 1024) master[i] = 0;

  // ---- biases (indexed by role wl)
  float eb1v = eb1[a * 128 + wl * 16 + ln], pb1v = pb1[a * 128 + wl * 16 + ln];
  float eb2v = eb2[a * 128 + wl * 16 + ln], pb2v = pb2[a * 128 + wl * 16 + ln];
  float db2v = db2[a * 128 + wl * 16 + ln];
  float hbm = 0.f, hbs = 0.f, d1b0 = 0.f, d1b1 = 0.f, dmsb = 0.f;
  float ghb[6] = {0.f, 0.f, 0.f, 0.f, 0.f, 0.f};
  if (wl < 2) { hbm = emb[a * 32 + wl * 16 + ln]; hbs = esb[a * 32 + wl * 16 + ln]; }
  else if (wl < 4) { hbm = pmb[a * 32 + (wl - 2) * 16 + ln]; hbs = psb[a * 32 + (wl - 2) * 16 + ln]; }
  if (wl < 4) { d1b0 = db1[a * 128 + wl * 16 + ln]; d1b1 = db1[a * 128 + (wl + 4) * 16 + ln]; }
  else {
    int kx = wl - 4;
#pragma unroll
    for (int g = 0; g < 3; ++g)
#pragma unroll
      for (int j = 0; j < 2; ++j)
        ghb[g * 2 + j] = bih[a * 384 + g * 128 + (kx + 4 * j) * 16 + ln]
                       + bhh[a * 384 + g * 128 + (kx + 4 * j) * 16 + ln];
  }
  if (wl == 0) dmsb = (ln < 2) ? dmb[a * 2 + ln] : (ln < 4) ? dsb[a * 2 + (ln - 2)] : 0.f;

  __syncthreads();

  // ---- stage y(0), x(0); eps(0)
  if (tid < 320) {
    int row = tid / 10, c = tid - row * 10;
    master[row * MS + 34 + c] = f2bf(states[((size_t)b0 + row) * 10 + c]);
  }
  if (tid >= 384 && tid < 448) {
    int i = tid - 384, row = i >> 1, c = i & 1;
    master[row * MS + c] = f2bf(states[((size_t)512 + b0 + row) * 10 + a * 2 + c]);
  }
  float e_cur[4] = {0.f, 0.f, 0.f, 0.f};
  if (wl < 2) {
#pragma unroll
    for (int q = 0; q < 4; ++q)
      e_cur[q] = eps[((size_t)(b0 + R + 4 * lg + q) * 5 + a) * 32 + wl * 16 + ln];
  }
  float xv[4] = {0.f, 0.f, 0.f, 0.f};
  float kl = 0.f, nll = 0.f;
  f32x4 em = {0, 0, 0, 0}, esv = {0, 0, 0, 0};
  f32x4 gh[3][2];
  float hn[8];
  __syncthreads();

  for (int t = 0; t < 127; ++t) {
    // ===== Phase A: enc1+pri1; wl0: prev dec-head + NLL =====
    if (wl == 0 && t > 0) {
      f32x4 acc = {dmsb, dmsb, dmsb, dmsb};
#pragma unroll
      for (int kb = 0; kb < 4; ++kb) {
        bf16x8 ad = *(const bf16x8*)&he[(R + ln) * TS + kb * 32 + lg * 8];
        bf16x8 bf = *(const bf16x8*)&dms_lds[kb * 512 + l * 8];
        acc = MFMA_B16(ad, bf, acc);
      }
#pragma unroll
      for (int q = 0; q < 4; ++q) {
        float sv = __shfl(splus_(acc[q]), l + 2);
        if (ln < 2) {
          float d = (xv[q] - acc[q]) / sv;
          nll += 0.9189385332f + __logf(sv) + 0.5f * d * d;
        }
      }
    }
    {
      bf16x8 f1[6], f2[5];
#pragma unroll
      for (int kb = 0; kb < 6; ++kb) f1[kb] = LD_FRAG(FO_ENC1 + wl * 6 + kb);
#pragma unroll
      for (int kb = 0; kb < 5; ++kb) f2[kb] = LD_FRAG(FO_PRI1 + wl * 5 + kb);
      bf16x8 am[6];
#pragma unroll
      for (int kb = 0; kb < 6; ++kb)
        am[kb] = *(const bf16x8*)&master[(R + ln) * MS + kb * 32 + lg * 8];
      f32x4 a1 = {eb1v, eb1v, eb1v, eb1v}, a2 = {pb1v, pb1v, pb1v, pb1v};
#pragma unroll
      for (int kb = 0; kb < 6; ++kb) a1 = MFMA_B16(am[kb], f1[kb], a1);
#pragma unroll
      for (int kb = 0; kb < 5; ++kb) a2 = MFMA_B16(am[kb + 1], f2[kb], a2);
#pragma unroll
      for (int q = 0; q < 4; ++q) {
        t1e[(R + 4 * lg + q) * TS + wl * 16 + ln] = f2bf(fmaxf(a1[q], 0.f));
        t1p[(R + 4 * lg + q) * TS + wl * 16 + ln] = f2bf(fmaxf(a2[q], 0.f));
      }
    }
    __syncthreads();

    // ===== Phase B: enc2 -> he, pri2 -> hp =====
    {
      bf16x8 g1[4], g2[4];
#pragma unroll
      for (int kb = 0; kb < 4; ++kb) {
        g1[kb] = LD_FRAG(FO_ENC2 + wl * 4 + kb);
        g2[kb] = LD_FRAG(FO_PRI2 + wl * 4 + kb);
      }
      bf16x8 ae[4], ap[4];
#pragma unroll
      for (int kb = 0; kb < 4; ++kb) {
        ae[kb] = *(const bf16x8*)&t1e[(R + ln) * TS + kb * 32 + lg * 8];
        ap[kb] = *(const bf16x8*)&t1p[(R + ln) * TS + kb * 32 + lg * 8];
      }
      f32x4 a1 = {eb2v, eb2v, eb2v, eb2v}, a2 = {pb2v, pb2v, pb2v, pb2v};
#pragma unroll
      for (int kb = 0; kb < 4; ++kb) {
        a1 = MFMA_B16(ae[kb], g1[kb], a1);
        a2 = MFMA_B16(ap[kb], g2[kb], a2);
      }
#pragma unroll
      for (int q = 0; q < 4; ++q) {
        he[(R + 4 * lg + q) * TS + wl * 16 + ln] = f2bf(fmaxf(a1[q], 0.f));
        hp[(R + 4 * lg + q) * TS + wl * 16 + ln] = f2bf(fmaxf(a2[q], 0.f));
      }
    }
    __syncthreads();

    // ===== Phase C: heads + z (wl0-3, ms streamed); ghh (wl4-7, LDS) =====
    if (wl < 4) {
      const unsigned short* hs = (wl < 2) ? he : hp;
      int fbase = FO_MS + ((wl < 2) ? 0 : 16) + (wl & 1) * 4;
      bf16x8 fm[4], fs[4];
#pragma unroll
      for (int kb = 0; kb < 4; ++kb) {
        fm[kb] = LD_FRAG(fbase + kb);
        fs[kb] = LD_FRAG(fbase + 8 + kb);
      }
      bf16x8 ah[4];
#pragma unroll
      for (int kb = 0; kb < 4; ++kb)
        ah[kb] = *(const bf16x8*)&hs[(R + ln) * TS + kb * 32 + lg * 8];
      f32x4 m = {hbm, hbm, hbm, hbm}, s = {hbs, hbs, hbs, hbs};
#pragma unroll
      for (int kb = 0; kb < 4; ++kb) {
        m = MFMA_B16(ah[kb], fm[kb], m);
        s = MFMA_B16(ah[kb], fs[kb], s);
      }
      if (wl < 2) {
        em = m;
#pragma unroll
        for (int q = 0; q < 4; ++q) {
          esv[q] = splus_(s[q]);
          master[(R + 4 * lg + q) * MS + 2 + wl * 16 + ln] = f2bf(m[q] + esv[q] * e_cur[q]);
        }
      } else {
#pragma unroll
        for (int q = 0; q < 4; ++q) {
          msbuf[0][R + 4 * lg + q][(wl - 2) * 16 + ln] = m[q];
          msbuf[1][R + 4 * lg + q][(wl - 2) * 16 + ln] = splus_(s[q]);
        }
      }
    } else {
      int kx = wl - 4;
      bf16x8 ahh[4];
#pragma unroll
      for (int kb = 0; kb < 4; ++kb)
        ahh[kb] = *(const bf16x8*)&master[(R + ln) * MS + (kb + 2) * 32 + lg * 8];
#pragma unroll
      for (int g = 0; g < 3; ++g)
#pragma unroll
        for (int j = 0; j < 2; ++j) {
          float bv = ghb[g * 2 + j];
          gh[g][j] = (f32x4){bv, bv, bv, bv};
        }
#pragma unroll
      for (int kb = 0; kb < 4; ++kb)
#pragma unroll
        for (int g = 0; g < 3; ++g)
#pragma unroll
          for (int j = 0; j < 2; ++j)
            gh[g][j] = MFMA_B16(ahh[kb],
              *(const bf16x8*)&ghh_lds[(size_t)((g * 8 + kx + 4 * j) * 4 + kb) * 512 + l * 8],
              gh[g][j]);
    }
    __syncthreads();

    // ===== Phase D: eps(t+1); dec1 + KL (wl0-3); gih + GRU (wl4-7); xv (wl0) =====
    if (wl < 2 && t < 126) {
#pragma unroll
      for (int q = 0; q < 4; ++q)
        e_cur[q] = eps[((size_t)((t + 1) * 512 + b0 + R + 4 * lg + q) * 5 + a) * 32 + wl * 16 + ln];
    }
    if (wl == 0) {
#pragma unroll
      for (int q = 0; q < 4; ++q)
        xv[q] = states[((size_t)(t + 1) * 512 + b0 + R + 4 * lg + q) * 10 + a * 2 + (ln & 1)];
    }
    if (wl < 4) {
      bf16x8 fd[12];
#pragma unroll
      for (int j = 0; j < 2; ++j)
#pragma unroll
        for (int kb = 0; kb < 6; ++kb)
          fd[j * 6 + kb] = LD_FRAG(FO_DEC1 + (wl + 4 * j) * 6 + kb);
      bf16x8 amn[6];
#pragma unroll
      for (int kb = 0; kb < 6; ++kb)
        amn[kb] = *(const bf16x8*)&master[(R + ln) * MS + kb * 32 + lg * 8];
#pragma unroll
      for (int j = 0; j < 2; ++j) {
        float bv = (j == 0) ? d1b0 : d1b1;
        f32x4 acc = {bv, bv, bv, bv};
#pragma unroll
        for (int kb = 0; kb < 6; ++kb) acc = MFMA_B16(amn[kb], fd[j * 6 + kb], acc);
#pragma unroll
        for (int q = 0; q < 4; ++q)
          t1e[(R + 4 * lg + q) * TS + (wl + 4 * j) * 16 + ln] = f2bf(fmaxf(acc[q], 0.f));
      }
      if (wl < 2) {
#pragma unroll
        for (int q = 0; q < 4; ++q) {
          float pm = msbuf[0][R + 4 * lg + q][wl * 16 + ln];
          float ps = msbuf[1][R + 4 * lg + q][wl * 16 + ln];
          float dm = em[q] - pm;
          float es2 = esv[q] * esv[q];
          kl += 0.5f * (2.f * __logf(ps) - 2.f * __logf(esv[q]) + (es2 + dm * dm) / (ps * ps) - 1.f);
        }
      }
    } else {
      int kx = wl - 4;
      bf16x8 fg[12];
#pragma unroll
      for (int g = 0; g < 3; ++g)
#pragma unroll
        for (int j = 0; j < 2; ++j)
#pragma unroll
          for (int kb = 0; kb < 2; ++kb)
            fg[g * 4 + j * 2 + kb] = LD_FRAG(FO_GIH + (g * 8 + kx + 4 * j) * 2 + kb);
      bf16x8 am2[2];
#pragma unroll
      for (int kb = 0; kb < 2; ++kb)
        am2[kb] = *(const bf16x8*)&master[(R + ln) * MS + kb * 32 + lg * 8];
      f32x4 gi[3][2];
#pragma unroll
      for (int g = 0; g < 3; ++g)
#pragma unroll
        for (int j = 0; j < 2; ++j) gi[g][j] = (f32x4){0.f, 0.f, 0.f, 0.f};
#pragma unroll
      for (int kb = 0; kb < 2; ++kb)
#pragma unroll
        for (int g = 0; g < 3; ++g)
#pragma unroll
          for (int j = 0; j < 2; ++j)
            gi[g][j] = MFMA_B16(am2[kb], fg[g * 4 + j * 2 + kb], gi[g][j]);
#pragma unroll
      for (int j = 0; j < 2; ++j)
#pragma unroll
        for (int q = 0; q < 4; ++q) {
          float r_ = sigm_(gi[0][j][q] + gh[0][j][q]);
          float u_ = sigm_(gi[1][j][q] + gh[1][j][q]);
          float n_ = tanh_(gi[2][j][q] + r_ * gh[2][j][q]);
          float ho = bf2f(master[(R + 4 * lg + q) * MS + 64 + (kx + 4 * j) * 16 + ln]);
          hn[j * 4 + q] = (1.f - u_) * n_ + u_ * ho;
        }
    }
    __syncthreads();

    // ===== Phase E: dec2 -> he(hd); h write (wl4-7); stage y(t+1) w1-5, x(t+2) w6 =====
    {
      bf16x8 fd2[4];
#pragma unroll
      for (int kb = 0; kb < 4; ++kb) fd2[kb] = LD_FRAG(FO_DEC2 + wl * 4 + kb);
      bf16x8 ad[4];
#pragma unroll
      for (int kb = 0; kb < 4; ++kb)
        ad[kb] = *(const bf16x8*)&t1e[(R + ln) * TS + kb * 32 + lg * 8];
      f32x4 acc = {db2v, db2v, db2v, db2v};
#pragma unroll
      for (int kb = 0; kb < 4; ++kb) acc = MFMA_B16(ad[kb], fd2[kb], acc);
#pragma unroll
      for (int q = 0; q < 4; ++q)
        he[(R + 4 * lg + q) * TS + wl * 16 + ln] = f2bf(fmaxf(acc[q], 0.f));
    }
    if (wl >= 4) {
      int kx = wl - 4;
#pragma unroll
      for (int j = 0; j < 2; ++j)
#pragma unroll
        for (int q = 0; q < 4; ++q)
          master[(R + 4 * lg + q) * MS + 64 + (kx + 4 * j) * 16 + ln] = f2bf(hn[j * 4 + q]);
    }
    if (t < 126) {
      if (w >= 1 && w <= 5) {
        int i = (w - 1) * 64 + l;   // 0..319
        int row = i / 10, c = i - row * 10;
        master[row * MS + 34 + c] = f2bf(states[((size_t)(t + 1) * 512 + b0 + row) * 10 + c]);
      }
      if (w == 6) {
        int row = l >> 1, c = l & 1;
        master[row * MS + c] = f2bf(states[((size_t)(t + 2) * 512 + b0 + row) * 10 + a * 2 + c]);
      }
    }
    __syncthreads();
  }

  // ---- epilogue: finish step 126 (dec head + NLL) on wl0 waves
  if (wl == 0) {
    f32x4 acc = {dmsb, dmsb, dmsb, dmsb};
#pragma unroll
    for (int kb = 0; kb < 4; ++kb) {
      bf16x8 ad = *(const bf16x8*)&he[(R + ln) * TS + kb * 32 + lg * 8];
      bf16x8 bf = *(const bf16x8*)&dms_lds[kb * 512 + l * 8];
      acc = MFMA_B16(ad, bf, acc);
    }
#pragma unroll
    for (int q = 0; q < 4; ++q) {
      float sv = __shfl(splus_(acc[q]), l + 2);
      if (ln < 2) {
        float d = (xv[q] - acc[q]) / sv;
        nll += 0.9189385332f + __logf(sv) + 0.5f * d * d;
      }
    }
  }

  // ---- final reduction (16 waves)
#pragma unroll
  for (int off = 32; off > 0; off >>= 1) {
    kl += __shfl_down(kl, off);
    nll += __shfl_down(nll, off);
  }
  if (l == 0) { red[w] = kl; red[16 + w] = nll; }
  __syncthreads();
  if (tid == 0) {
    float K = 0.f, N = 0.f;
#pragma unroll
    for (int i = 0; i < 16; ++i) { K += red[i]; N += red[16 + i]; }
    atomicAdd(out, K);
    atomicAdd(out + 1, N);
  }
}

extern "C" void kernel_launch(void* const* d_in, const int* in_sizes, int n_in,
                              void* d_out, int out_size, void* d_ws, size_t ws_size,
                              hipStream_t stream) {
  (void)in_sizes; (void)n_in; (void)out_size; (void)ws_size;
  const float* states = (const float*)d_in[0];
  const float* eps    = (const float*)d_in[1];
  const float* ew1 = (const float*)d_in[2];
  const float* eb1 = (const float*)d_in[3];
  const float* ew2 = (const float*)d_in[4];
  const float* eb2 = (const float*)d_in[5];
  const float* emw = (const float*)d_in[6];
  const float* emb = (const float*)d_in[7];
  const float* esw = (const float*)d_in[8];
  const float* esb = (const float*)d_in[9];
  const float* pw1 = (const float*)d_in[10];
  const float* pb1 = (const float*)d_in[11];
  const float* pw2 = (const float*)d_in[12];
  const float* pb2 = (const float*)d_in[13];
  const float* pmw = (const float*)d_in[14];
  const float* pmb = (const float*)d_in[15];
  const float* psw = (const float*)d_in[16];
  const float* psb = (const float*)d_in[17];
  const float* dw1 = (const float*)d_in[18];
  const float* db1 = (const float*)d_in[19];
  const float* dw2 = (const float*)d_in[20];
  const float* db2 = (const float*)d_in[21];
  const float* dmw = (const float*)d_in[22];
  const float* dmb = (const float*)d_in[23];
  const float* dsw = (const float*)d_in[24];
  const float* dsb = (const float*)d_in[25];
  const float* wih = (const float*)d_in[26];
  const float* whh = (const float*)d_in[27];
  const float* bih = (const float*)d_in[28];
  const float* bhh = (const float*)d_in[29];

  unsigned short* frags = (unsigned short*)d_ws;
  float* out = (float*)d_out;

  hipMemsetAsync(d_out, 0, 2 * sizeof(float), stream);
  prep_kernel<<<dim3(5 * NFRAG), dim3(64), 0, stream>>>(
      ew1, pw1, dw1, wih, whh, ew2, pw2, dw2, emw, esw, pmw, psw, dmw, dsw, frags);
  vrnn_main<<<dim3(16, 5), dim3(1024), 0, stream>>>(
      states, eps, eb1, eb2, emb, esb, pb1, pb2, pmb, psb,
      db1, db2, dmb, dsb, bih, bhh, frags, out);
}

// Round 11
// 1032.045 us; speedup vs baseline: 3.8236x; 3.8236x over previous
//
#include <hip/hip_runtime.h>

typedef __attribute__((ext_vector_type(8))) short bf16x8;
typedef __attribute__((ext_vector_type(4))) float f32x4;

#define MFMA_B16(A,B,C) __builtin_amdgcn_mfma_f32_16x16x32_bf16((A),(B),(C),0,0,0)

// ---- fragment layout constants (units: fragments of 1KB = 64 lanes * 8 bf16) ----
#define FO_ENC1 0
#define FO_PRI1 48
#define FO_DEC1 88
#define FO_GIH  136
#define FO_GHH  184
#define FO_ENC2 280
#define FO_PRI2 312
#define FO_DEC2 344
#define FO_MS   376
#define FO_DECMS 408
#define NFRAG   412

#define MS 200
#define TS 136

__device__ __forceinline__ unsigned short f2bf(float f) {
  union { float f; unsigned u; } v; v.f = f;
  unsigned r = (v.u + 0x7fffu + ((v.u >> 16) & 1u)) >> 16;
  return (unsigned short)r;
}
__device__ __forceinline__ float bf2f(unsigned short h) {
  union { unsigned u; float f; } v; v.u = ((unsigned)h) << 16;
  return v.f;
}
__device__ __forceinline__ float sigm_(float x) { return 1.f / (1.f + __expf(-x)); }
__device__ __forceinline__ float tanh_(float x) {
  x = fminf(fmaxf(x, -15.f), 15.f);
  float e = __expf(-2.f * x);
  return (1.f - e) / (1.f + e);
}
__device__ __forceinline__ float splus_(float x) {
  return fmaxf(x, 0.f) + log1pf(__expf(-fabsf(x)));
}

// ============================ PREP KERNEL ============================
// Master activation k-layout: [x:0..1 | z:2..33 | y:34..43 | pad:44..63 | h:64..191]
// Fragment (64 lanes x 8 bf16): lane l, elem j -> B[mk = kb*32 + (l>>4)*8 + j][n = nt*16 + (l&15)]
__global__ void prep_kernel(const float* __restrict__ ew1, const float* __restrict__ pw1,
                            const float* __restrict__ dw1, const float* __restrict__ wih,
                            const float* __restrict__ whh, const float* __restrict__ ew2,
                            const float* __restrict__ pw2, const float* __restrict__ dw2,
                            const float* __restrict__ emw, const float* __restrict__ esw,
                            const float* __restrict__ pmw, const float* __restrict__ psw,
                            const float* __restrict__ dmw, const float* __restrict__ dsw,
                            unsigned short* __restrict__ ws)
{
  int blk = blockIdx.x;
  int a = blk / NFRAG, f = blk % NFRAG;
  int l = threadIdx.x, lg = l >> 4, ln = l & 15;
  float v[8];

  if (f < FO_PRI1) {                       // enc1: [x, y, h]
    int fi = f, nt = fi / 6, kb = fi % 6, n = nt * 16 + ln;
#pragma unroll
    for (int j = 0; j < 8; ++j) {
      int mk = kb * 32 + lg * 8 + j;
      int r = (mk < 2) ? mk : (mk >= 34 && mk < 44) ? 2 + (mk - 34)
            : (mk >= 64) ? 12 + (mk - 64) : -1;
      v[j] = (r >= 0) ? ew1[((size_t)a * 140 + r) * 128 + n] : 0.f;
    }
  } else if (f < FO_DEC1) {                // pri1: [y, h]
    int fi = f - FO_PRI1, nt = fi / 5, kb = 1 + fi % 5, n = nt * 16 + ln;
#pragma unroll
    for (int j = 0; j < 8; ++j) {
      int mk = kb * 32 + lg * 8 + j;
      int r = (mk >= 34 && mk < 44) ? (mk - 34) : (mk >= 64) ? 10 + (mk - 64) : -1;
      v[j] = (r >= 0) ? pw1[((size_t)a * 138 + r) * 128 + n] : 0.f;
    }
  } else if (f < FO_GIH) {                 // dec1: [y, z, h]
    int fi = f - FO_DEC1, nt = fi / 6, kb = fi % 6, n = nt * 16 + ln;
#pragma unroll
    for (int j = 0; j < 8; ++j) {
      int mk = kb * 32 + lg * 8 + j;
      int r = (mk >= 2 && mk < 34) ? 10 + (mk - 2) : (mk >= 34 && mk < 44) ? (mk - 34)
            : (mk >= 64) ? 42 + (mk - 64) : -1;
      v[j] = (r >= 0) ? dw1[((size_t)a * 170 + r) * 128 + n] : 0.f;
    }
  } else if (f < FO_GHH) {                 // gru_ih: [x, z], N=384
    int fi = f - FO_GIH, nt = fi / 2, kb = fi % 2, n = nt * 16 + ln;
#pragma unroll
    for (int j = 0; j < 8; ++j) {
      int mk = kb * 32 + lg * 8 + j;
      v[j] = (mk < 34) ? wih[((size_t)a * 34 + mk) * 384 + n] : 0.f;
    }
  } else if (f < FO_ENC2) {                // gru_hh: K=128, N=384
    int fi = f - FO_GHH, nt = fi / 4, kb = fi % 4, n = nt * 16 + ln;
#pragma unroll
    for (int j = 0; j < 8; ++j) {
      int r = kb * 32 + lg * 8 + j;
      v[j] = whh[((size_t)a * 128 + r) * 384 + n];
    }
  } else if (f < FO_DEC2) {                // enc2 / pri2
    int fi = f - FO_ENC2;
    const float* W = (fi < 32) ? ew2 : pw2;
    fi &= 31;
    int nt = fi / 4, kb = fi % 4, n = nt * 16 + ln;
#pragma unroll
    for (int j = 0; j < 8; ++j) {
      int r = kb * 32 + lg * 8 + j;
      v[j] = W[((size_t)a * 128 + r) * 128 + n];
    }
  } else if (f < FO_MS) {                  // dec2
    int fi = f - FO_DEC2, nt = fi / 4, kb = fi % 4, n = nt * 16 + ln;
#pragma unroll
    for (int j = 0; j < 8; ++j) {
      int r = kb * 32 + lg * 8 + j;
      v[j] = dw2[((size_t)a * 128 + r) * 128 + n];
    }
  } else if (f < FO_DECMS) {               // enc_m / enc_s / pri_m / pri_s (N=32)
    int fi = f - FO_MS, mat = fi / 8, rem = fi % 8, nt = rem / 4, kb = rem % 4;
    int n = nt * 16 + ln;
    const float* W = (mat == 0) ? emw : (mat == 1) ? esw : (mat == 2) ? pmw : psw;
#pragma unroll
    for (int j = 0; j < 8; ++j) {
      int r = kb * 32 + lg * 8 + j;
      v[j] = W[((size_t)a * 128 + r) * 32 + n];
    }
  } else {                                 // dec m/s packed
    int kb = f - FO_DECMS;
#pragma unroll
    for (int j = 0; j < 8; ++j) {
      int r = kb * 32 + lg * 8 + j;
      v[j] = (ln < 2) ? dmw[((size_t)a * 128 + r) * 2 + ln]
           : (ln < 4) ? dsw[((size_t)a * 128 + r) * 2 + (ln - 2)] : 0.f;
    }
  }
  unsigned short* dst = ws + (size_t)blk * 512 + l * 8;
#pragma unroll
  for (int j = 0; j < 8; ++j) dst[j] = f2bf(v[j]);
}

// ============================ MAIN KERNEL ============================
// grid (32,5): 16 rows/block, 256 threads = 4 waves.
// KEY: VGPR budget/wave = 65536/blockSize (measured R1-R10) -> 256 VGPRs at 256 thr.
// Each wave owns n-tiles {w, w+4} of every 128-wide matrix and gates g*8+{w,w+4} of
// the GRU matrices. ghh/ms/dms pinned in LDS; other weights stream from L2 (resident).
// Phases: A(enc1,pri1 | w0: prev dec-head+NLL) | B(enc2,pri2) |
//   C(heads all waves; z+eps-reload w0/1; ghh all waves) |
//   D(dec1; gih+GRU; KL w0/1; xv w0) | E(dec2; h-write; stage y/x(t+1))
#define LD_FRAG(idx) (*(const bf16x8*)(fa + (size_t)(idx) * 512 + l * 8))

__global__ __launch_bounds__(256, 1) void vrnn_main(
    const float* __restrict__ states, const float* __restrict__ eps,
    const float* __restrict__ eb1, const float* __restrict__ eb2,
    const float* __restrict__ emb, const float* __restrict__ esb,
    const float* __restrict__ pb1, const float* __restrict__ pb2,
    const float* __restrict__ pmb, const float* __restrict__ psb,
    const float* __restrict__ db1, const float* __restrict__ db2,
    const float* __restrict__ dmb, const float* __restrict__ dsb,
    const float* __restrict__ bih, const float* __restrict__ bhh,
    const unsigned short* __restrict__ frags, float* __restrict__ out)
{
  const int a = blockIdx.y;
  const int b0 = blockIdx.x * 16;
  const int tid = threadIdx.x;
  const int w = tid >> 6, l = tid & 63, lg = l >> 4, ln = l & 15;

  __shared__ __align__(16) unsigned short ghh_lds[96 * 512];   // 98304 B
  __shared__ __align__(16) unsigned short ms_lds[32 * 512];    // 32768 B
  __shared__ __align__(16) unsigned short dms_lds[4 * 512];    //  4096 B
  __shared__ __align__(16) unsigned short master[16 * MS];     //  6400 B
  __shared__ __align__(16) unsigned short t1e[16 * TS], t1p[16 * TS];
  __shared__ __align__(16) unsigned short he[16 * TS], hp[16 * TS];  // 17408 B total
  __shared__ float msbuf[2][16][32];                           //  4096 B
  __shared__ float red[8];

  const unsigned short* fa = frags + (size_t)a * NFRAG * 512;

  // ---- pin LDS weight sets (once)
  {
    const uint4* s1 = (const uint4*)(fa + (size_t)FO_GHH * 512);
    uint4* d1 = (uint4*)ghh_lds;
    for (int i = tid; i < 96 * 64; i += 256) d1[i] = s1[i];
    const uint4* s2 = (const uint4*)(fa + (size_t)FO_MS * 512);
    uint4* d2 = (uint4*)ms_lds;
    for (int i = tid; i < 32 * 64; i += 256) d2[i] = s2[i];
    const uint4* s3 = (const uint4*)(fa + (size_t)FO_DECMS * 512);
    uint4* d3 = (uint4*)dms_lds;
    d3[tid] = s3[tid];
  }
  for (int i = tid; i < 16 * MS; i += 256) master[i] = 0;

  // ---- biases (2 n-tiles per wave)
  float eb1v[2], pb1v[2], eb2v[2], pb2v[2], db2v[2], d1b[2], ghb[3][2];
#pragma unroll
  for (int j = 0; j < 2; ++j) {
    int n = (w + 4 * j) * 16 + ln;
    eb1v[j] = eb1[a * 128 + n]; pb1v[j] = pb1[a * 128 + n];
    eb2v[j] = eb2[a * 128 + n]; pb2v[j] = pb2[a * 128 + n];
    db2v[j] = db2[a * 128 + n]; d1b[j]  = db1[a * 128 + n];
#pragma unroll
    for (int g = 0; g < 3; ++g)
      ghb[g][j] = bih[a * 384 + g * 128 + n] + bhh[a * 384 + g * 128 + n];
  }
  float hbm, hbs, dmsb = 0.f;
  if (w < 2) { hbm = emb[a * 32 + w * 16 + ln]; hbs = esb[a * 32 + w * 16 + ln]; }
  else { hbm = pmb[a * 32 + (w - 2) * 16 + ln]; hbs = psb[a * 32 + (w - 2) * 16 + ln]; }
  if (w == 0) dmsb = (ln < 2) ? dmb[a * 2 + ln] : (ln < 4) ? dsb[a * 2 + (ln - 2)] : 0.f;

  __syncthreads();

  // ---- stage y(0), x(0)
  if (tid < 160) {
    int row = tid / 10, c = tid - row * 10;
    master[row * MS + 34 + c] = f2bf(states[(size_t)b0 * 10 + tid]);
  }
  if (tid >= 192 && tid < 224) {
    int i = tid - 192, row = i >> 1, c = i & 1;
    master[row * MS + c] = f2bf(states[((size_t)512 + b0 + row) * 10 + a * 2 + c]);
  }
  float e_cur[4] = {0.f, 0.f, 0.f, 0.f};
  if (w < 2) {
#pragma unroll
    for (int q = 0; q < 4; ++q)
      e_cur[q] = eps[((size_t)(b0 + 4 * lg + q) * 5 + a) * 32 + w * 16 + ln];
  }
  float xv[4] = {0.f, 0.f, 0.f, 0.f};
  float kl = 0.f, nll = 0.f;
  f32x4 em = {0, 0, 0, 0}, esv = {0, 0, 0, 0};
  f32x4 gh[3][2];
  float hn[8];
  __syncthreads();

  for (int t = 0; t < 127; ++t) {
    // ===== Phase A: enc1+pri1 (n = w, w+4); w0: prev dec-head + NLL =====
    if (w == 0 && t > 0) {
      f32x4 acc = {dmsb, dmsb, dmsb, dmsb};
#pragma unroll
      for (int kb = 0; kb < 4; ++kb) {
        bf16x8 ad = *(const bf16x8*)&he[ln * TS + kb * 32 + lg * 8];
        bf16x8 bf = *(const bf16x8*)&dms_lds[kb * 512 + l * 8];
        acc = MFMA_B16(ad, bf, acc);
      }
#pragma unroll
      for (int q = 0; q < 4; ++q) {
        float sv = __shfl(splus_(acc[q]), l + 2);
        if (ln < 2) {
          float d = (xv[q] - acc[q]) / sv;
          nll += 0.9189385332f + __logf(sv) + 0.5f * d * d;
        }
      }
    }
    {
      bf16x8 f1[12], f2[10];
#pragma unroll
      for (int j = 0; j < 2; ++j) {
#pragma unroll
        for (int kb = 0; kb < 6; ++kb) f1[j * 6 + kb] = LD_FRAG(FO_ENC1 + (w + 4 * j) * 6 + kb);
#pragma unroll
        for (int kb = 0; kb < 5; ++kb) f2[j * 5 + kb] = LD_FRAG(FO_PRI1 + (w + 4 * j) * 5 + kb);
      }
      bf16x8 am[6];
#pragma unroll
      for (int kb = 0; kb < 6; ++kb)
        am[kb] = *(const bf16x8*)&master[ln * MS + kb * 32 + lg * 8];
#pragma unroll
      for (int j = 0; j < 2; ++j) {
        f32x4 a1 = {eb1v[j], eb1v[j], eb1v[j], eb1v[j]};
        f32x4 a2 = {pb1v[j], pb1v[j], pb1v[j], pb1v[j]};
#pragma unroll
        for (int kb = 0; kb < 6; ++kb) a1 = MFMA_B16(am[kb], f1[j * 6 + kb], a1);
#pragma unroll
        for (int kb = 0; kb < 5; ++kb) a2 = MFMA_B16(am[kb + 1], f2[j * 5 + kb], a2);
#pragma unroll
        for (int q = 0; q < 4; ++q) {
          t1e[(4 * lg + q) * TS + (w + 4 * j) * 16 + ln] = f2bf(fmaxf(a1[q], 0.f));
          t1p[(4 * lg + q) * TS + (w + 4 * j) * 16 + ln] = f2bf(fmaxf(a2[q], 0.f));
        }
      }
    }
    __syncthreads();

    // ===== Phase B: enc2 -> he, pri2 -> hp (n = w, w+4) =====
    {
      bf16x8 g1[8], g2[8];
#pragma unroll
      for (int j = 0; j < 2; ++j)
#pragma unroll
        for (int kb = 0; kb < 4; ++kb) {
          g1[j * 4 + kb] = LD_FRAG(FO_ENC2 + (w + 4 * j) * 4 + kb);
          g2[j * 4 + kb] = LD_FRAG(FO_PRI2 + (w + 4 * j) * 4 + kb);
        }
      bf16x8 ae[4], ap[4];
#pragma unroll
      for (int kb = 0; kb < 4; ++kb) {
        ae[kb] = *(const bf16x8*)&t1e[ln * TS + kb * 32 + lg * 8];
        ap[kb] = *(const bf16x8*)&t1p[ln * TS + kb * 32 + lg * 8];
      }
#pragma unroll
      for (int j = 0; j < 2; ++j) {
        f32x4 a1 = {eb2v[j], eb2v[j], eb2v[j], eb2v[j]};
        f32x4 a2 = {pb2v[j], pb2v[j], pb2v[j], pb2v[j]};
#pragma unroll
        for (int kb = 0; kb < 4; ++kb) {
          a1 = MFMA_B16(ae[kb], g1[j * 4 + kb], a1);
          a2 = MFMA_B16(ap[kb], g2[j * 4 + kb], a2);
        }
#pragma unroll
        for (int q = 0; q < 4; ++q) {
          he[(4 * lg + q) * TS + (w + 4 * j) * 16 + ln] = f2bf(fmaxf(a1[q], 0.f));
          hp[(4 * lg + q) * TS + (w + 4 * j) * 16 + ln] = f2bf(fmaxf(a2[q], 0.f));
        }
      }
    }
    __syncthreads();

    // ===== Phase C: heads (all waves) + z (w0/1) + eps reload; ghh (all waves) =====
    {
      const unsigned short* hs = (w < 2) ? he : hp;
      int mbase = ((w < 2) ? 0 : 16) + (w & 1) * 4;
      bf16x8 ah[4];
#pragma unroll
      for (int kb = 0; kb < 4; ++kb)
        ah[kb] = *(const bf16x8*)&hs[ln * TS + kb * 32 + lg * 8];
      f32x4 m = {hbm, hbm, hbm, hbm}, s = {hbs, hbs, hbs, hbs};
#pragma unroll
      for (int kb = 0; kb < 4; ++kb) {
        m = MFMA_B16(ah[kb], *(const bf16x8*)&ms_lds[(mbase + kb) * 512 + l * 8], m);
        s = MFMA_B16(ah[kb], *(const bf16x8*)&ms_lds[(mbase + 8 + kb) * 512 + l * 8], s);
      }
      if (w < 2) {
        em = m;
#pragma unroll
        for (int q = 0; q < 4; ++q) {
          esv[q] = splus_(s[q]);
          master[(4 * lg + q) * MS + 2 + w * 16 + ln] = f2bf(m[q] + esv[q] * e_cur[q]);
        }
        if (t < 126) {
#pragma unroll
          for (int q = 0; q < 4; ++q)
            e_cur[q] = eps[((size_t)((t + 1) * 512 + b0 + 4 * lg + q) * 5 + a) * 32 + w * 16 + ln];
        }
      } else {
#pragma unroll
        for (int q = 0; q < 4; ++q) {
          msbuf[0][4 * lg + q][(w - 2) * 16 + ln] = m[q];
          msbuf[1][4 * lg + q][(w - 2) * 16 + ln] = splus_(s[q]);
        }
      }
      // ghh (reads master h region only -- no race with z writes above)
      bf16x8 ahh[4];
#pragma unroll
      for (int kb = 0; kb < 4; ++kb)
        ahh[kb] = *(const bf16x8*)&master[ln * MS + (kb + 2) * 32 + lg * 8];
#pragma unroll
      for (int g = 0; g < 3; ++g)
#pragma unroll
        for (int j = 0; j < 2; ++j) {
          float bv = ghb[g][j];
          gh[g][j] = (f32x4){bv, bv, bv, bv};
        }
#pragma unroll
      for (int kb = 0; kb < 4; ++kb)
#pragma unroll
        for (int g = 0; g < 3; ++g)
#pragma unroll
          for (int j = 0; j < 2; ++j)
            gh[g][j] = MFMA_B16(ahh[kb],
              *(const bf16x8*)&ghh_lds[(size_t)((g * 8 + w + 4 * j) * 4 + kb) * 512 + l * 8],
              gh[g][j]);
    }
    __syncthreads();

    // ===== Phase D: dec1 + gih + GRU (all waves); KL (w0/1); xv (w0) =====
    {
      if (w == 0) {
#pragma unroll
        for (int q = 0; q < 4; ++q)
          xv[q] = states[((size_t)(t + 1) * 512 + b0 + 4 * lg + q) * 10 + a * 2 + (ln & 1)];
      }
      bf16x8 fd[12], fg[12];
#pragma unroll
      for (int j = 0; j < 2; ++j)
#pragma unroll
        for (int kb = 0; kb < 6; ++kb)
          fd[j * 6 + kb] = LD_FRAG(FO_DEC1 + (w + 4 * j) * 6 + kb);
#pragma unroll
      for (int g = 0; g < 3; ++g)
#pragma unroll
        for (int j = 0; j < 2; ++j)
#pragma unroll
          for (int kb = 0; kb < 2; ++kb)
            fg[g * 4 + j * 2 + kb] = LD_FRAG(FO_GIH + (g * 8 + w + 4 * j) * 2 + kb);
      bf16x8 am[6];
#pragma unroll
      for (int kb = 0; kb < 6; ++kb)
        am[kb] = *(const bf16x8*)&master[ln * MS + kb * 32 + lg * 8];
#pragma unroll
      for (int j = 0; j < 2; ++j) {
        f32x4 acc = {d1b[j], d1b[j], d1b[j], d1b[j]};
#pragma unroll
        for (int kb = 0; kb < 6; ++kb) acc = MFMA_B16(am[kb], fd[j * 6 + kb], acc);
#pragma unroll
        for (int q = 0; q < 4; ++q)
          t1e[(4 * lg + q) * TS + (w + 4 * j) * 16 + ln] = f2bf(fmaxf(acc[q], 0.f));
      }
      f32x4 gi[3][2];
#pragma unroll
      for (int g = 0; g < 3; ++g)
#pragma unroll
        for (int j = 0; j < 2; ++j) gi[g][j] = (f32x4){0.f, 0.f, 0.f, 0.f};
#pragma unroll
      for (int kb = 0; kb < 2; ++kb)
#pragma unroll
        for (int g = 0; g < 3; ++g)
#pragma unroll
          for (int j = 0; j < 2; ++j)
            gi[g][j] = MFMA_B16(am[kb], fg[g * 4 + j * 2 + kb], gi[g][j]);
#pragma unroll
      for (int j = 0; j < 2; ++j)
#pragma unroll
        for (int q = 0; q < 4; ++q) {
          float r_ = sigm_(gi[0][j][q] + gh[0][j][q]);
          float u_ = sigm_(gi[1][j][q] + gh[1][j][q]);
          float n_ = tanh_(gi[2][j][q] + r_ * gh[2][j][q]);
          float ho = bf2f(master[(4 * lg + q) * MS + 64 + (w + 4 * j) * 16 + ln]);
          hn[j * 4 + q] = (1.f - u_) * n_ + u_ * ho;
        }
      if (w < 2) {
#pragma unroll
        for (int q = 0; q < 4; ++q) {
          float pm = msbuf[0][4 * lg + q][w * 16 + ln];
          float ps = msbuf[1][4 * lg + q][w * 16 + ln];
          float dm = em[q] - pm;
          float es2 = esv[q] * esv[q];
          kl += 0.5f * (2.f * __logf(ps) - 2.f * __logf(esv[q]) + (es2 + dm * dm) / (ps * ps) - 1.f);
        }
      }
    }
    __syncthreads();

    // ===== Phase E: dec2 -> he(hd); h write; stage y(t+1), x(t+2) =====
    {
      bf16x8 fd2[8];
#pragma unroll
      for (int j = 0; j < 2; ++j)
#pragma unroll
        for (int kb = 0; kb < 4; ++kb)
          fd2[j * 4 + kb] = LD_FRAG(FO_DEC2 + (w + 4 * j) * 4 + kb);
      bf16x8 ad[4];
#pragma unroll
      for (int kb = 0; kb < 4; ++kb)
        ad[kb] = *(const bf16x8*)&t1e[ln * TS + kb * 32 + lg * 8];
#pragma unroll
      for (int j = 0; j < 2; ++j) {
        f32x4 acc = {db2v[j], db2v[j], db2v[j], db2v[j]};
#pragma unroll
        for (int kb = 0; kb < 4; ++kb) acc = MFMA_B16(ad[kb], fd2[j * 4 + kb], acc);
#pragma unroll
        for (int q = 0; q < 4; ++q)
          he[(4 * lg + q) * TS + (w + 4 * j) * 16 + ln] = f2bf(fmaxf(acc[q], 0.f));
      }
#pragma unroll
      for (int j = 0; j < 2; ++j)
#pragma unroll
        for (int q = 0; q < 4; ++q)
          master[(4 * lg + q) * MS + 64 + (w + 4 * j) * 16 + ln] = f2bf(hn[j * 4 + q]);
      if (t < 126) {
        if (w >= 1) {
          int i = (w - 1) * 64 + l;   // 0..191, need 0..159
          if (i < 160) {
            int row = i / 10, c = i - row * 10;
            master[row * MS + 34 + c] = f2bf(states[((size_t)(t + 1) * 512 + b0) * 10 + i]);
          }
        }
        if (w == 0 && l < 32) {
          int row = l >> 1, c = l & 1;
          master[row * MS + c] = f2bf(states[((size_t)(t + 2) * 512 + b0 + row) * 10 + a * 2 + c]);
        }
      }
    }
    __syncthreads();
  }

  // ---- epilogue: finish step 126 (dec head + NLL) on w0
  if (w == 0) {
    f32x4 acc = {dmsb, dmsb, dmsb, dmsb};
#pragma unroll
    for (int kb = 0; kb < 4; ++kb) {
      bf16x8 ad = *(const bf16x8*)&he[ln * TS + kb * 32 + lg * 8];
      bf16x8 bf = *(const bf16x8*)&dms_lds[kb * 512 + l * 8];
      acc = MFMA_B16(ad, bf, acc);
    }
#pragma unroll
    for (int q = 0; q < 4; ++q) {
      float sv = __shfl(splus_(acc[q]), l + 2);
      if (ln < 2) {
        float d = (xv[q] - acc[q]) / sv;
        nll += 0.9189385332f + __logf(sv) + 0.5f * d * d;
      }
    }
  }

  // ---- final reduction (4 waves)
#pragma unroll
  for (int off = 32; off > 0; off >>= 1) {
    kl += __shfl_down(kl, off);
    nll += __shfl_down(nll, off);
  }
  if (l == 0) { red[w] = kl; red[4 + w] = nll; }
  __syncthreads();
  if (tid == 0) {
    float K = 0.f, N = 0.f;
#pragma unroll
    for (int i = 0; i < 4; ++i) { K += red[i]; N += red[4 + i]; }
    atomicAdd(out, K);
    atomicAdd(out + 1, N);
  }
}

extern "C" void kernel_launch(void* const* d_in, const int* in_sizes, int n_in,
                              void* d_out, int out_size, void* d_ws, size_t ws_size,
                              hipStream_t stream) {
  (void)in_sizes; (void)n_in; (void)out_size; (void)ws_size;
  const float* states = (const float*)d_in[0];
  const float* eps    = (const float*)d_in[1];
  const float* ew1 = (const float*)d_in[2];
  const float* eb1 = (const float*)d_in[3];
  const float* ew2 = (const float*)d_in[4];
  const float* eb2 = (const float*)d_in[5];
  const float* emw = (const float*)d_in[6];
  const float* emb = (const float*)d_in[7];
  const float* esw = (const float*)d_in[8];
  const float* esb = (const float*)d_in[9];
  const float* pw1 = (const float*)d_in[10];
  const float* pb1 = (const float*)d_in[11];
  const float* pw2 = (const float*)d_in[12];
  const float* pb2 = (const float*)d_in[13];
  const float* pmw = (const float*)d_in[14];
  const float* pmb = (const float*)d_in[15];
  const float* psw = (const float*)d_in[16];
  const float* psb = (const float*)d_in[17];
  const float* dw1 = (const float*)d_in[18];
  const float* db1 = (const float*)d_in[19];
  const float* dw2 = (const float*)d_in[20];
  const float* db2 = (const float*)d_in[21];
  const float* dmw = (const float*)d_in[22];
  const float* dmb = (const float*)d_in[23];
  const float* dsw = (const float*)d_in[24];
  const float* dsb = (const float*)d_in[25];
  const float* wih = (const float*)d_in[26];
  const float* whh = (const float*)d_in[27];
  const float* bih = (const float*)d_in[28];
  const float* bhh = (const float*)d_in[29];

  unsigned short* frags = (unsigned short*)d_ws;
  float* out = (float*)d_out;

  hipMemsetAsync(d_out, 0, 2 * sizeof(float), stream);
  prep_kernel<<<dim3(5 * NFRAG), dim3(64), 0, stream>>>(
      ew1, pw1, dw1, wih, whh, ew2, pw2, dw2, emw, esw, pmw, psw, dmw, dsw, frags);
  vrnn_main<<<dim3(32, 5), dim3(256), 0, stream>>>(
      states, eps, eb1, eb2, emb, esb, pb1, pb2, pmb, psb,
      db1, db2, dmb, dsb, bih, bhh, frags, out);
}

// Round 12
// 1013.360 us; speedup vs baseline: 3.8941x; 1.0184x over previous
//
#include <hip/hip_runtime.h>

typedef __attribute__((ext_vector_type(8))) short bf16x8;
typedef __attribute__((ext_vector_type(4))) float f32x4;

#define MFMA_B16(A,B,C) __builtin_amdgcn_mfma_f32_16x16x32_bf16((A),(B),(C),0,0,0)

// ---- fragment layout constants (units: fragments of 1KB = 64 lanes * 8 bf16) ----
#define FO_ENC1 0
#define FO_PRI1 48
#define FO_DEC1 88
#define FO_GIH  136
#define FO_GHH  184
#define FO_ENC2 280
#define FO_PRI2 312
#define FO_DEC2 344
#define FO_MS   376
#define FO_DECMS 408
#define NFRAG   412

#define MS 200
#define TS 136

__device__ __forceinline__ unsigned short f2bf(float f) {
  union { float f; unsigned u; } v; v.f = f;
  unsigned r = (v.u + 0x7fffu + ((v.u >> 16) & 1u)) >> 16;
  return (unsigned short)r;
}
__device__ __forceinline__ float bf2f(unsigned short h) {
  union { unsigned u; float f; } v; v.u = ((unsigned)h) << 16;
  return v.f;
}
__device__ __forceinline__ float sigm_(float x) { return 1.f / (1.f + __expf(-x)); }
__device__ __forceinline__ float tanh_(float x) {
  x = fminf(fmaxf(x, -15.f), 15.f);
  float e = __expf(-2.f * x);
  return (1.f - e) / (1.f + e);
}
__device__ __forceinline__ float splus_(float x) {
  return fmaxf(x, 0.f) + log1pf(__expf(-fabsf(x)));
}
// non-temporal float load: stream data must not evict the L2 weight working set
__device__ __forceinline__ float ldnt(const float* p) {
  return __builtin_nontemporal_load(p);
}

// ============================ PREP KERNEL ============================
// Master activation k-layout: [x:0..1 | z:2..33 | y:34..43 | pad:44..63 | h:64..191]
// Fragment (64 lanes x 8 bf16): lane l, elem j -> B[mk = kb*32 + (l>>4)*8 + j][n = nt*16 + (l&15)]
__global__ void prep_kernel(const float* __restrict__ ew1, const float* __restrict__ pw1,
                            const float* __restrict__ dw1, const float* __restrict__ wih,
                            const float* __restrict__ whh, const float* __restrict__ ew2,
                            const float* __restrict__ pw2, const float* __restrict__ dw2,
                            const float* __restrict__ emw, const float* __restrict__ esw,
                            const float* __restrict__ pmw, const float* __restrict__ psw,
                            const float* __restrict__ dmw, const float* __restrict__ dsw,
                            unsigned short* __restrict__ ws)
{
  int blk = blockIdx.x;
  int a = blk / NFRAG, f = blk % NFRAG;
  int l = threadIdx.x, lg = l >> 4, ln = l & 15;
  float v[8];

  if (f < FO_PRI1) {                       // enc1: [x, y, h]
    int fi = f, nt = fi / 6, kb = fi % 6, n = nt * 16 + ln;
#pragma unroll
    for (int j = 0; j < 8; ++j) {
      int mk = kb * 32 + lg * 8 + j;
      int r = (mk < 2) ? mk : (mk >= 34 && mk < 44) ? 2 + (mk - 34)
            : (mk >= 64) ? 12 + (mk - 64) : -1;
      v[j] = (r >= 0) ? ew1[((size_t)a * 140 + r) * 128 + n] : 0.f;
    }
  } else if (f < FO_DEC1) {                // pri1: [y, h]
    int fi = f - FO_PRI1, nt = fi / 5, kb = 1 + fi % 5, n = nt * 16 + ln;
#pragma unroll
    for (int j = 0; j < 8; ++j) {
      int mk = kb * 32 + lg * 8 + j;
      int r = (mk >= 34 && mk < 44) ? (mk - 34) : (mk >= 64) ? 10 + (mk - 64) : -1;
      v[j] = (r >= 0) ? pw1[((size_t)a * 138 + r) * 128 + n] : 0.f;
    }
  } else if (f < FO_GIH) {                 // dec1: [y, z, h]
    int fi = f - FO_DEC1, nt = fi / 6, kb = fi % 6, n = nt * 16 + ln;
#pragma unroll
    for (int j = 0; j < 8; ++j) {
      int mk = kb * 32 + lg * 8 + j;
      int r = (mk >= 2 && mk < 34) ? 10 + (mk - 2) : (mk >= 34 && mk < 44) ? (mk - 34)
            : (mk >= 64) ? 42 + (mk - 64) : -1;
      v[j] = (r >= 0) ? dw1[((size_t)a * 170 + r) * 128 + n] : 0.f;
    }
  } else if (f < FO_GHH) {                 // gru_ih: [x, z], N=384
    int fi = f - FO_GIH, nt = fi / 2, kb = fi % 2, n = nt * 16 + ln;
#pragma unroll
    for (int j = 0; j < 8; ++j) {
      int mk = kb * 32 + lg * 8 + j;
      v[j] = (mk < 34) ? wih[((size_t)a * 34 + mk) * 384 + n] : 0.f;
    }
  } else if (f < FO_ENC2) {                // gru_hh: K=128, N=384
    int fi = f - FO_GHH, nt = fi / 4, kb = fi % 4, n = nt * 16 + ln;
#pragma unroll
    for (int j = 0; j < 8; ++j) {
      int r = kb * 32 + lg * 8 + j;
      v[j] = whh[((size_t)a * 128 + r) * 384 + n];
    }
  } else if (f < FO_DEC2) {                // enc2 / pri2
    int fi = f - FO_ENC2;
    const float* W = (fi < 32) ? ew2 : pw2;
    fi &= 31;
    int nt = fi / 4, kb = fi % 4, n = nt * 16 + ln;
#pragma unroll
    for (int j = 0; j < 8; ++j) {
      int r = kb * 32 + lg * 8 + j;
      v[j] = W[((size_t)a * 128 + r) * 128 + n];
    }
  } else if (f < FO_MS) {                  // dec2
    int fi = f - FO_DEC2, nt = fi / 4, kb = fi % 4, n = nt * 16 + ln;
#pragma unroll
    for (int j = 0; j < 8; ++j) {
      int r = kb * 32 + lg * 8 + j;
      v[j] = dw2[((size_t)a * 128 + r) * 128 + n];
    }
  } else if (f < FO_DECMS) {               // enc_m / enc_s / pri_m / pri_s (N=32)
    int fi = f - FO_MS, mat = fi / 8, rem = fi % 8, nt = rem / 4, kb = rem % 4;
    int n = nt * 16 + ln;
    const float* W = (mat == 0) ? emw : (mat == 1) ? esw : (mat == 2) ? pmw : psw;
#pragma unroll
    for (int j = 0; j < 8; ++j) {
      int r = kb * 32 + lg * 8 + j;
      v[j] = W[((size_t)a * 128 + r) * 32 + n];
    }
  } else {                                 // dec m/s packed
    int kb = f - FO_DECMS;
#pragma unroll
    for (int j = 0; j < 8; ++j) {
      int r = kb * 32 + lg * 8 + j;
      v[j] = (ln < 2) ? dmw[((size_t)a * 128 + r) * 2 + ln]
           : (ln < 4) ? dsw[((size_t)a * 128 + r) * 2 + (ln - 2)] : 0.f;
    }
  }
  unsigned short* dst = ws + (size_t)blk * 512 + l * 8;
#pragma unroll
  for (int j = 0; j < 8; ++j) dst[j] = f2bf(v[j]);
}

// ============================ MAIN KERNEL ============================
// grid (32,5): 16 rows/block, 256 threads = 4 waves, 256 VGPRs/wave (no spills, R11).
// Each wave owns n-tiles {w, w+4} of every 128-wide matrix and gates g*8+{w,w+4}.
// ghh/ms/dms pinned in LDS; other weights stream from L2 at point of use.
// R12 changes: (1) eps/states loads NON-TEMPORAL so the streams stop evicting the
// L2 weight working set; (2) eps(t+1) reload moved from phase C to phase D top
// (HBM latency overlaps dec1+gih+GRU instead of stalling C's end barrier).
#define LD_FRAG(idx) (*(const bf16x8*)(fa + (size_t)(idx) * 512 + l * 8))

__global__ __launch_bounds__(256, 1) void vrnn_main(
    const float* __restrict__ states, const float* __restrict__ eps,
    const float* __restrict__ eb1, const float* __restrict__ eb2,
    const float* __restrict__ emb, const float* __restrict__ esb,
    const float* __restrict__ pb1, const float* __restrict__ pb2,
    const float* __restrict__ pmb, const float* __restrict__ psb,
    const float* __restrict__ db1, const float* __restrict__ db2,
    const float* __restrict__ dmb, const float* __restrict__ dsb,
    const float* __restrict__ bih, const float* __restrict__ bhh,
    const unsigned short* __restrict__ frags, float* __restrict__ out)
{
  const int a = blockIdx.y;
  const int b0 = blockIdx.x * 16;
  const int tid = threadIdx.x;
  const int w = tid >> 6, l = tid & 63, lg = l >> 4, ln = l & 15;

  __shared__ __align__(16) unsigned short ghh_lds[96 * 512];   // 98304 B
  __shared__ __align__(16) unsigned short ms_lds[32 * 512];    // 32768 B
  __shared__ __align__(16) unsigned short dms_lds[4 * 512];    //  4096 B
  __shared__ __align__(16) unsigned short master[16 * MS];     //  6400 B
  __shared__ __align__(16) unsigned short t1e[16 * TS], t1p[16 * TS];
  __shared__ __align__(16) unsigned short he[16 * TS], hp[16 * TS];  // 17408 B total
  __shared__ float msbuf[2][16][32];                           //  4096 B
  __shared__ float red[8];

  const unsigned short* fa = frags + (size_t)a * NFRAG * 512;

  // ---- pin LDS weight sets (once)
  {
    const uint4* s1 = (const uint4*)(fa + (size_t)FO_GHH * 512);
    uint4* d1 = (uint4*)ghh_lds;
    for (int i = tid; i < 96 * 64; i += 256) d1[i] = s1[i];
    const uint4* s2 = (const uint4*)(fa + (size_t)FO_MS * 512);
    uint4* d2 = (uint4*)ms_lds;
    for (int i = tid; i < 32 * 64; i += 256) d2[i] = s2[i];
    const uint4* s3 = (const uint4*)(fa + (size_t)FO_DECMS * 512);
    uint4* d3 = (uint4*)dms_lds;
    d3[tid] = s3[tid];
  }
  for (int i = tid; i < 16 * MS; i += 256) master[i] = 0;

  // ---- biases (2 n-tiles per wave)
  float eb1v[2], pb1v[2], eb2v[2], pb2v[2], db2v[2], d1b[2], ghb[3][2];
#pragma unroll
  for (int j = 0; j < 2; ++j) {
    int n = (w + 4 * j) * 16 + ln;
    eb1v[j] = eb1[a * 128 + n]; pb1v[j] = pb1[a * 128 + n];
    eb2v[j] = eb2[a * 128 + n]; pb2v[j] = pb2[a * 128 + n];
    db2v[j] = db2[a * 128 + n]; d1b[j]  = db1[a * 128 + n];
#pragma unroll
    for (int g = 0; g < 3; ++g)
      ghb[g][j] = bih[a * 384 + g * 128 + n] + bhh[a * 384 + g * 128 + n];
  }
  float hbm, hbs, dmsb = 0.f;
  if (w < 2) { hbm = emb[a * 32 + w * 16 + ln]; hbs = esb[a * 32 + w * 16 + ln]; }
  else { hbm = pmb[a * 32 + (w - 2) * 16 + ln]; hbs = psb[a * 32 + (w - 2) * 16 + ln]; }
  if (w == 0) dmsb = (ln < 2) ? dmb[a * 2 + ln] : (ln < 4) ? dsb[a * 2 + (ln - 2)] : 0.f;

  __syncthreads();

  // ---- stage y(0), x(0) (non-temporal: stream data)
  if (tid < 160) {
    int row = tid / 10, c = tid - row * 10;
    master[row * MS + 34 + c] = f2bf(ldnt(states + (size_t)b0 * 10 + tid));
  }
  if (tid >= 192 && tid < 224) {
    int i = tid - 192, row = i >> 1, c = i & 1;
    master[row * MS + c] = f2bf(ldnt(states + ((size_t)512 + b0 + row) * 10 + a * 2 + c));
  }
  float e_cur[4] = {0.f, 0.f, 0.f, 0.f};
  if (w < 2) {
#pragma unroll
    for (int q = 0; q < 4; ++q)
      e_cur[q] = ldnt(eps + ((size_t)(b0 + 4 * lg + q) * 5 + a) * 32 + w * 16 + ln);
  }
  float xv[4] = {0.f, 0.f, 0.f, 0.f};
  float kl = 0.f, nll = 0.f;
  f32x4 em = {0, 0, 0, 0}, esv = {0, 0, 0, 0};
  f32x4 gh[3][2];
  float hn[8];
  __syncthreads();

  for (int t = 0; t < 127; ++t) {
    // ===== Phase A: enc1+pri1 (n = w, w+4); w0: prev dec-head + NLL =====
    if (w == 0 && t > 0) {
      f32x4 acc = {dmsb, dmsb, dmsb, dmsb};
#pragma unroll
      for (int kb = 0; kb < 4; ++kb) {
        bf16x8 ad = *(const bf16x8*)&he[ln * TS + kb * 32 + lg * 8];
        bf16x8 bf = *(const bf16x8*)&dms_lds[kb * 512 + l * 8];
        acc = MFMA_B16(ad, bf, acc);
      }
#pragma unroll
      for (int q = 0; q < 4; ++q) {
        float sv = __shfl(splus_(acc[q]), l + 2);
        if (ln < 2) {
          float d = (xv[q] - acc[q]) / sv;
          nll += 0.9189385332f + __logf(sv) + 0.5f * d * d;
        }
      }
    }
    {
      bf16x8 f1[12], f2[10];
#pragma unroll
      for (int j = 0; j < 2; ++j) {
#pragma unroll
        for (int kb = 0; kb < 6; ++kb) f1[j * 6 + kb] = LD_FRAG(FO_ENC1 + (w + 4 * j) * 6 + kb);
#pragma unroll
        for (int kb = 0; kb < 5; ++kb) f2[j * 5 + kb] = LD_FRAG(FO_PRI1 + (w + 4 * j) * 5 + kb);
      }
      bf16x8 am[6];
#pragma unroll
      for (int kb = 0; kb < 6; ++kb)
        am[kb] = *(const bf16x8*)&master[ln * MS + kb * 32 + lg * 8];
#pragma unroll
      for (int j = 0; j < 2; ++j) {
        f32x4 a1 = {eb1v[j], eb1v[j], eb1v[j], eb1v[j]};
        f32x4 a2 = {pb1v[j], pb1v[j], pb1v[j], pb1v[j]};
#pragma unroll
        for (int kb = 0; kb < 6; ++kb) a1 = MFMA_B16(am[kb], f1[j * 6 + kb], a1);
#pragma unroll
        for (int kb = 0; kb < 5; ++kb) a2 = MFMA_B16(am[kb + 1], f2[j * 5 + kb], a2);
#pragma unroll
        for (int q = 0; q < 4; ++q) {
          t1e[(4 * lg + q) * TS + (w + 4 * j) * 16 + ln] = f2bf(fmaxf(a1[q], 0.f));
          t1p[(4 * lg + q) * TS + (w + 4 * j) * 16 + ln] = f2bf(fmaxf(a2[q], 0.f));
        }
      }
    }
    __syncthreads();

    // ===== Phase B: enc2 -> he, pri2 -> hp (n = w, w+4) =====
    {
      bf16x8 g1[8], g2[8];
#pragma unroll
      for (int j = 0; j < 2; ++j)
#pragma unroll
        for (int kb = 0; kb < 4; ++kb) {
          g1[j * 4 + kb] = LD_FRAG(FO_ENC2 + (w + 4 * j) * 4 + kb);
          g2[j * 4 + kb] = LD_FRAG(FO_PRI2 + (w + 4 * j) * 4 + kb);
        }
      bf16x8 ae[4], ap[4];
#pragma unroll
      for (int kb = 0; kb < 4; ++kb) {
        ae[kb] = *(const bf16x8*)&t1e[ln * TS + kb * 32 + lg * 8];
        ap[kb] = *(const bf16x8*)&t1p[ln * TS + kb * 32 + lg * 8];
      }
#pragma unroll
      for (int j = 0; j < 2; ++j) {
        f32x4 a1 = {eb2v[j], eb2v[j], eb2v[j], eb2v[j]};
        f32x4 a2 = {pb2v[j], pb2v[j], pb2v[j], pb2v[j]};
#pragma unroll
        for (int kb = 0; kb < 4; ++kb) {
          a1 = MFMA_B16(ae[kb], g1[j * 4 + kb], a1);
          a2 = MFMA_B16(ap[kb], g2[j * 4 + kb], a2);
        }
#pragma unroll
        for (int q = 0; q < 4; ++q) {
          he[(4 * lg + q) * TS + (w + 4 * j) * 16 + ln] = f2bf(fmaxf(a1[q], 0.f));
          hp[(4 * lg + q) * TS + (w + 4 * j) * 16 + ln] = f2bf(fmaxf(a2[q], 0.f));
        }
      }
    }
    __syncthreads();

    // ===== Phase C: heads (all waves) + z (w0/1); ghh (all waves) =====
    {
      const unsigned short* hs = (w < 2) ? he : hp;
      int mbase = ((w < 2) ? 0 : 16) + (w & 1) * 4;
      bf16x8 ah[4];
#pragma unroll
      for (int kb = 0; kb < 4; ++kb)
        ah[kb] = *(const bf16x8*)&hs[ln * TS + kb * 32 + lg * 8];
      f32x4 m = {hbm, hbm, hbm, hbm}, s = {hbs, hbs, hbs, hbs};
#pragma unroll
      for (int kb = 0; kb < 4; ++kb) {
        m = MFMA_B16(ah[kb], *(const bf16x8*)&ms_lds[(mbase + kb) * 512 + l * 8], m);
        s = MFMA_B16(ah[kb], *(const bf16x8*)&ms_lds[(mbase + 8 + kb) * 512 + l * 8], s);
      }
      if (w < 2) {
        em = m;
#pragma unroll
        for (int q = 0; q < 4; ++q) {
          esv[q] = splus_(s[q]);
          master[(4 * lg + q) * MS + 2 + w * 16 + ln] = f2bf(m[q] + esv[q] * e_cur[q]);
        }
      } else {
#pragma unroll
        for (int q = 0; q < 4; ++q) {
          msbuf[0][4 * lg + q][(w - 2) * 16 + ln] = m[q];
          msbuf[1][4 * lg + q][(w - 2) * 16 + ln] = splus_(s[q]);
        }
      }
      // ghh (reads master h region only -- no race with z writes above)
      bf16x8 ahh[4];
#pragma unroll
      for (int kb = 0; kb < 4; ++kb)
        ahh[kb] = *(const bf16x8*)&master[ln * MS + (kb + 2) * 32 + lg * 8];
#pragma unroll
      for (int g = 0; g < 3; ++g)
#pragma unroll
        for (int j = 0; j < 2; ++j) {
          float bv = ghb[g][j];
          gh[g][j] = (f32x4){bv, bv, bv, bv};
        }
#pragma unroll
      for (int kb = 0; kb < 4; ++kb)
#pragma unroll
        for (int g = 0; g < 3; ++g)
#pragma unroll
          for (int j = 0; j < 2; ++j)
            gh[g][j] = MFMA_B16(ahh[kb],
              *(const bf16x8*)&ghh_lds[(size_t)((g * 8 + w + 4 * j) * 4 + kb) * 512 + l * 8],
              gh[g][j]);
    }
    __syncthreads();

    // ===== Phase D: eps(t+1) + xv FIRST (overlap with dec1+gih+GRU); KL (w0/1) =====
    {
      if (w < 2 && t < 126) {
#pragma unroll
        for (int q = 0; q < 4; ++q)
          e_cur[q] = ldnt(eps + ((size_t)((t + 1) * 512 + b0 + 4 * lg + q) * 5 + a) * 32
                          + w * 16 + ln);
      }
      if (w == 0) {
#pragma unroll
        for (int q = 0; q < 4; ++q)
          xv[q] = ldnt(states + ((size_t)(t + 1) * 512 + b0 + 4 * lg + q) * 10
                       + a * 2 + (ln & 1));
      }
      bf16x8 fd[12], fg[12];
#pragma unroll
      for (int j = 0; j < 2; ++j)
#pragma unroll
        for (int kb = 0; kb < 6; ++kb)
          fd[j * 6 + kb] = LD_FRAG(FO_DEC1 + (w + 4 * j) * 6 + kb);
#pragma unroll
      for (int g = 0; g < 3; ++g)
#pragma unroll
        for (int j = 0; j < 2; ++j)
#pragma unroll
          for (int kb = 0; kb < 2; ++kb)
            fg[g * 4 + j * 2 + kb] = LD_FRAG(FO_GIH + (g * 8 + w + 4 * j) * 2 + kb);
      bf16x8 am[6];
#pragma unroll
      for (int kb = 0; kb < 6; ++kb)
        am[kb] = *(const bf16x8*)&master[ln * MS + kb * 32 + lg * 8];
#pragma unroll
      for (int j = 0; j < 2; ++j) {
        f32x4 acc = {d1b[j], d1b[j], d1b[j], d1b[j]};
#pragma unroll
        for (int kb = 0; kb < 6; ++kb) acc = MFMA_B16(am[kb], fd[j * 6 + kb], acc);
#pragma unroll
        for (int q = 0; q < 4; ++q)
          t1e[(4 * lg + q) * TS + (w + 4 * j) * 16 + ln] = f2bf(fmaxf(acc[q], 0.f));
      }
      f32x4 gi[3][2];
#pragma unroll
      for (int g = 0; g < 3; ++g)
#pragma unroll
        for (int j = 0; j < 2; ++j) gi[g][j] = (f32x4){0.f, 0.f, 0.f, 0.f};
#pragma unroll
      for (int kb = 0; kb < 2; ++kb)
#pragma unroll
        for (int g = 0; g < 3; ++g)
#pragma unroll
          for (int j = 0; j < 2; ++j)
            gi[g][j] = MFMA_B16(am[kb], fg[g * 4 + j * 2 + kb], gi[g][j]);
#pragma unroll
      for (int j = 0; j < 2; ++j)
#pragma unroll
        for (int q = 0; q < 4; ++q) {
          float r_ = sigm_(gi[0][j][q] + gh[0][j][q]);
          float u_ = sigm_(gi[1][j][q] + gh[1][j][q]);
          float n_ = tanh_(gi[2][j][q] + r_ * gh[2][j][q]);
          float ho = bf2f(master[(4 * lg + q) * MS + 64 + (w + 4 * j) * 16 + ln]);
          hn[j * 4 + q] = (1.f - u_) * n_ + u_ * ho;
        }
      if (w < 2) {
#pragma unroll
        for (int q = 0; q < 4; ++q) {
          float pm = msbuf[0][4 * lg + q][w * 16 + ln];
          float ps = msbuf[1][4 * lg + q][w * 16 + ln];
          float dm = em[q] - pm;
          float es2 = esv[q] * esv[q];
          kl += 0.5f * (2.f * __logf(ps) - 2.f * __logf(esv[q]) + (es2 + dm * dm) / (ps * ps) - 1.f);
        }
      }
    }
    __syncthreads();

    // ===== Phase E: dec2 -> he(hd); h write; stage y(t+1), x(t+2) =====
    {
      bf16x8 fd2[8];
#pragma unroll
      for (int j = 0; j < 2; ++j)
#pragma unroll
        for (int kb = 0; kb < 4; ++kb)
          fd2[j * 4 + kb] = LD_FRAG(FO_DEC2 + (w + 4 * j) * 4 + kb);
      bf16x8 ad[4];
#pragma unroll
      for (int kb = 0; kb < 4; ++kb)
        ad[kb] = *(const bf16x8*)&t1e[ln * TS + kb * 32 + lg * 8];
#pragma unroll
      for (int j = 0; j < 2; ++j) {
        f32x4 acc = {db2v[j], db2v[j], db2v[j], db2v[j]};
#pragma unroll
        for (int kb = 0; kb < 4; ++kb) acc = MFMA_B16(ad[kb], fd2[j * 4 + kb], acc);
#pragma unroll
        for (int q = 0; q < 4; ++q)
          he[(4 * lg + q) * TS + (w + 4 * j) * 16 + ln] = f2bf(fmaxf(acc[q], 0.f));
      }
#pragma unroll
      for (int j = 0; j < 2; ++j)
#pragma unroll
        for (int q = 0; q < 4; ++q)
          master[(4 * lg + q) * MS + 64 + (w + 4 * j) * 16 + ln] = f2bf(hn[j * 4 + q]);
      if (t < 126) {
        if (w >= 1) {
          int i = (w - 1) * 64 + l;   // 0..191, need 0..159
          if (i < 160) {
            int row = i / 10, c = i - row * 10;
            master[row * MS + 34 + c] =
              f2bf(ldnt(states + ((size_t)(t + 1) * 512 + b0) * 10 + i));
          }
        }
        if (w == 0 && l < 32) {
          int row = l >> 1, c = l & 1;
          master[row * MS + c] =
            f2bf(ldnt(states + ((size_t)(t + 2) * 512 + b0 + row) * 10 + a * 2 + c));
        }
      }
    }
    __syncthreads();
  }

  // ---- epilogue: finish step 126 (dec head + NLL) on w0
  if (w == 0) {
    f32x4 acc = {dmsb, dmsb, dmsb, dmsb};
#pragma unroll
    for (int kb = 0; kb < 4; ++kb) {
      bf16x8 ad = *(const bf16x8*)&he[ln * TS + kb * 32 + lg * 8];
      bf16x8 bf = *(const bf16x8*)&dms_lds[kb * 512 + l * 8];
      acc = MFMA_B16(ad, bf, acc);
    }
#pragma unroll
    for (int q = 0; q < 4; ++q) {
      float sv = __shfl(splus_(acc[q]), l + 2);
      if (ln < 2) {
        float d = (xv[q] - acc[q]) / sv;
        nll += 0.9189385332f + __logf(sv) + 0.5f * d * d;
      }
    }
  }

  // ---- final reduction (4 waves)
#pragma unroll
  for (int off = 32; off > 0; off >>= 1) {
    kl += __shfl_down(kl, off);
    nll += __shfl_down(nll, off);
  }
  if (l == 0) { red[w] = kl; red[4 + w] = nll; }
  __syncthreads();
  if (tid == 0) {
    float K = 0.f, N = 0.f;
#pragma unroll
    for (int i = 0; i < 4; ++i) { K += red[i]; N += red[4 + i]; }
    atomicAdd(out, K);
    atomicAdd(out + 1, N);
  }
}

extern "C" void kernel_launch(void* const* d_in, const int* in_sizes, int n_in,
                              void* d_out, int out_size, void* d_ws, size_t ws_size,
                              hipStream_t stream) {
  (void)in_sizes; (void)n_in; (void)out_size; (void)ws_size;
  const float* states = (const float*)d_in[0];
  const float* eps    = (const float*)d_in[1];
  const float* ew1 = (const float*)d_in[2];
  const float* eb1 = (const float*)d_in[3];
  const float* ew2 = (const float*)d_in[4];
  const float* eb2 = (const float*)d_in[5];
  const float* emw = (const float*)d_in[6];
  const float* emb = (const float*)d_in[7];
  const float* esw = (const float*)d_in[8];
  const float* esb = (const float*)d_in[9];
  const float* pw1 = (const float*)d_in[10];
  const float* pb1 = (const float*)d_in[11];
  const float* pw2 = (const float*)d_in[12];
  const float* pb2 = (const float*)d_in[13];
  const float* pmw = (const float*)d_in[14];
  const float* pmb = (const float*)d_in[15];
  const float* psw = (const float*)d_in[16];
  const float* psb = (const float*)d_in[17];
  const float* dw1 = (const float*)d_in[18];
  const float* db1 = (const float*)d_in[19];
  const float* dw2 = (const float*)d_in[20];
  const float* db2 = (const float*)d_in[21];
  const float* dmw = (const float*)d_in[22];
  const float* dmb = (const float*)d_in[23];
  const float* dsw = (const float*)d_in[24];
  const float* dsb = (const float*)d_in[25];
  const float* wih = (const float*)d_in[26];
  const float* whh = (const float*)d_in[27];
  const float* bih = (const float*)d_in[28];
  const float* bhh = (const float*)d_in[29];

  unsigned short* frags = (unsigned short*)d_ws;
  float* out = (float*)d_out;

  hipMemsetAsync(d_out, 0, 2 * sizeof(float), stream);
  prep_kernel<<<dim3(5 * NFRAG), dim3(64), 0, stream>>>(
      ew1, pw1, dw1, wih, whh, ew2, pw2, dw2, emw, esw, pmw, psw, dmw, dsw, frags);
  vrnn_main<<<dim3(32, 5), dim3(256), 0, stream>>>(
      states, eps, eb1, eb2, emb, esb, pb1, pb2, pmb, psb,
      db1, db2, dmb, dsb, bih, bhh, frags, out);
}